// Round 1
// 1595.239 us; speedup vs baseline: 1.1527x; 1.1527x over previous
//
#include <hip/hip_runtime.h>
#include <hip/hip_bf16.h>
#include <math.h>

#define D_EMB 2048
#define NH 16
#define DK 128
#define SEQN 128
#define DFF 8192
#define VOCAB 30000
#define NLAYERS 6
#define TOKF (SEQN * D_EMB)   // 262144 elements

typedef __attribute__((ext_vector_type(8))) short short8v;
typedef __attribute__((ext_vector_type(4))) float float4v;
typedef __hip_bfloat16 bf16;

#define GLOAD_LDS16(g, l)                                                      \
    __builtin_amdgcn_global_load_lds(                                          \
        (const __attribute__((address_space(1))) void*)(g),                    \
        (__attribute__((address_space(3))) void*)(l), 16, 0, 0)

// ---------------------------------------------------------------------------
// fp32 -> bf16 conversion, z-batched over up to 8 (src,dst) pairs.
// ---------------------------------------------------------------------------
struct CvtArgs {
    const float* src[8];
    bf16* dst[8];
};

__global__ __launch_bounds__(256) void cvt_kernel(CvtArgs args, int n4) {
    int i = blockIdx.x * 256 + threadIdx.x;
    if (i >= n4) return;
    const float4* s = (const float4*)args.src[blockIdx.z];
    float4 v = s[i];
    union { short4 s4; bf16 h[4]; } u;
    u.h[0] = __float2bfloat16(v.x);
    u.h[1] = __float2bfloat16(v.y);
    u.h[2] = __float2bfloat16(v.z);
    u.h[3] = __float2bfloat16(v.w);
    ((short4*)args.dst[blockIdx.z])[i] = u.s4;
}

// ---------------------------------------------------------------------------
// x[7] + sinusoidal PE -> X [128,2048] bf16
// ---------------------------------------------------------------------------
__global__ __launch_bounds__(256) void add_pe_kernel(const float* __restrict__ x,
                                                     bf16* __restrict__ out) {
    int idx = blockIdx.x * 256 + threadIdx.x;
    int l = idx >> 11;
    int d = idx & 2047;
    float two_i = (float)(d & ~1);
    float div = __expf(-9.210340371976184f * two_i * (1.0f / 2048.0f));
    float ang = (float)l * div;
    float pe = (d & 1) ? cosf(ang) : sinf(ang);
    out[idx] = __float2bfloat16(x[(size_t)7 * SEQN * D_EMB + idx] + pe);
}

// ---------------------------------------------------------------------------
// bf16 MFMA GEMM: C = A[M,K] @ B[N,K]^T, tile 64x64, BK=128, 4 waves,
// mfma_f32_16x16x32_bf16, global_load_lds width-16, XOR-16 LDS swizzle.
// NEW: double-buffered LDS + prefetch with counted s_waitcnt vmcnt(8) and
// raw s_barrier (no vmcnt(0) drain) -> hides K-step load latency at the
// low occupancy (1-2 blocks/CU) these small GEMMs run at.
// blockIdx.z = oi*ksplit + kh: oi selects (B,bias,C) set, kh the K-slice.
// out_bf16=1: bf16 C with bias/relu. out_bf16=0: fp32 partial at C+kh*M*N.
// ---------------------------------------------------------------------------
__global__ __launch_bounds__(256) void gemm_mfma_kernel(
    const bf16* __restrict__ A,
    const bf16* B0, const bf16* B1, const bf16* B2,
    const float* bias0, const float* bias1, const float* bias2,
    void* C0, void* C1, void* C2,
    int M, int N, int K, int relu, int out_bf16, int ksplit, int kslog)
{
    int z = blockIdx.z;
    int oi = z >> kslog;
    int kh = z & (ksplit - 1);
    int Klocal = K >> kslog;
    int kbase = kh * Klocal;

    const bf16* B    = (oi == 0) ? B0    : (oi == 1) ? B1    : B2;
    const float* bias = (oi == 0) ? bias0 : (oi == 1) ? bias1 : bias2;
    void* C          = (oi == 0) ? C0    : (oi == 1) ? C1    : C2;

    __shared__ __align__(16) bf16 As[2][64 * 128];   // 2 x 16 KB
    __shared__ __align__(16) bf16 Bs[2][64 * 128];   // 2 x 16 KB

    int tid = threadIdx.x;
    int w = tid >> 6;
    int lane = tid & 63;
    int m0 = blockIdx.x * 64;
    int n0 = blockIdx.y * 64;
    int wm = (w & 1) * 32;
    int wn = (w >> 1) * 32;
    int fcol = lane & 15;
    int fqu  = lane >> 4;
    int rr   = (w << 2) + (lane >> 4);   // row within 16-row chunk
    int scol = lane & 15;

    float4v acc[2][2];
    acc[0][0] = (float4v)0.0f; acc[0][1] = (float4v)0.0f;
    acc[1][0] = (float4v)0.0f; acc[1][1] = (float4v)0.0f;

    // 8 global_load_lds per wave per tile (4 A + 4 B)
    auto stage = [&](int buf, int k0) {
        #pragma unroll
        for (int t = 0; t < 4; ++t) {
            int r = t * 16 + rr;
            int s = scol ^ (r & 15);
            GLOAD_LDS16(A + (size_t)(m0 + r) * K + kbase + k0 + s * 8,
                        (char*)As[buf] + (size_t)(t * 16 + (w << 2)) * 256);
            GLOAD_LDS16(B + (size_t)(n0 + r) * K + kbase + k0 + s * 8,
                        (char*)Bs[buf] + (size_t)(t * 16 + (w << 2)) * 256);
        }
    };

    int nk = Klocal >> 7;
    stage(0, 0);
    for (int i = 0; i < nk; ++i) {
        int cur = i & 1;
        if (i + 1 < nk) {
            stage(cur ^ 1, (i + 1) << 7);                 // prefetch next tile
            asm volatile("s_waitcnt vmcnt(8)" ::: "memory");  // current tile done
        } else {
            asm volatile("s_waitcnt vmcnt(0)" ::: "memory");
        }
        __builtin_amdgcn_s_barrier();
        asm volatile("" ::: "memory");

        #pragma unroll
        for (int kk = 0; kk < 4; ++kk) {
            short8v a[2], b[2];
            int slog = kk * 4 + fqu;
            #pragma unroll
            for (int fm = 0; fm < 2; ++fm) {
                int m = wm + fm * 16 + fcol;
                a[fm] = *(const short8v*)((const char*)As[cur] + m * 256 + ((slog ^ (m & 15)) << 4));
            }
            #pragma unroll
            for (int fn = 0; fn < 2; ++fn) {
                int n = wn + fn * 16 + fcol;
                b[fn] = *(const short8v*)((const char*)Bs[cur] + n * 256 + ((slog ^ (n & 15)) << 4));
            }
            #pragma unroll
            for (int fm = 0; fm < 2; ++fm)
                #pragma unroll
                for (int fn = 0; fn < 2; ++fn)
                    acc[fm][fn] = __builtin_amdgcn_mfma_f32_16x16x32_bf16(
                        a[fm], b[fn], acc[fm][fn], 0, 0, 0);
        }
        asm volatile("" ::: "memory");
        __builtin_amdgcn_s_barrier();
    }

    int rbase = fqu * 4;
    #pragma unroll
    for (int fm = 0; fm < 2; ++fm) {
        #pragma unroll
        for (int fn = 0; fn < 2; ++fn) {
            int n = n0 + wn + fn * 16 + fcol;
            #pragma unroll
            for (int r = 0; r < 4; ++r) {
                int m = m0 + wm + fm * 16 + rbase + r;
                float v = acc[fm][fn][r];
                if (out_bf16) {
                    v += bias ? bias[n] : 0.0f;
                    if (relu) v = fmaxf(v, 0.0f);
                    ((bf16*)C)[(size_t)m * N + n] = __float2bfloat16(v);
                } else {
                    ((float*)C)[(size_t)kh * M * N + (size_t)m * N + n] = v;
                }
            }
        }
    }
}

// ---------------------------------------------------------------------------
// Per-token "attention" (faithful bug). One-pass online softmax, j-loop split
// across two thread-halves (256 threads), merged via LDS. Q/K/V arrive as
// fp32 split-K partial stacks (qparts / kvparts) or bf16 (cross K/V unused
// now, kept for flexibility).
// ---------------------------------------------------------------------------
__global__ __launch_bounds__(256) void attn_token_kernel(
    const float* __restrict__ qp,
    const float* __restrict__ kp, const float* __restrict__ vp,
    const bf16* __restrict__ k16, const bf16* __restrict__ v16,
    bf16* __restrict__ O, int causal, int qparts, int kvparts)
{
    int l = blockIdx.x;
    int tid = threadIdx.x;
    int i = tid & 127;
    int half = tid >> 7;
    __shared__ float qs[D_EMB];
    __shared__ float ks[D_EMB];
    __shared__ float vs[D_EMB];
    __shared__ float m1s[128], l1s[128];
    __shared__ float acc1s[128][NH + 1];
    size_t base = (size_t)l * D_EMB;

    for (int d = tid; d < D_EMB; d += 256) {
        float q = 0.0f;
        for (int p = 0; p < qparts; ++p) q += qp[(size_t)p * TOKF + base + d];
        qs[d] = q;
        if (kvparts) {
            float kv = 0.0f, vv = 0.0f;
            for (int p = 0; p < kvparts; ++p) {
                kv += kp[(size_t)p * TOKF + base + d];
                vv += vp[(size_t)p * TOKF + base + d];
            }
            ks[d] = kv; vs[d] = vv;
        } else {
            ks[d] = (float)k16[base + d];
            vs[d] = (float)v16[base + d];
        }
    }
    __syncthreads();

    const float scale = 0.088388347648318447f;  // 1/sqrt(128)
    float qr[NH];
    #pragma unroll
    for (int h = 0; h < NH; ++h) qr[h] = qs[h * DK + i];

    int jmax = causal ? (i + 1) : DK;
    int j0 = half * 64;
    int j1 = (jmax < j0 + 64) ? jmax : (j0 + 64);

    float m = -INFINITY, lsum = 0.0f;
    float acc[NH];
    #pragma unroll
    for (int h = 0; h < NH; ++h) acc[h] = 0.0f;

    for (int j = j0; j < j1; ++j) {
        float s0 = 0.0f, s1 = 0.0f, s2 = 0.0f, s3 = 0.0f;
        #pragma unroll
        for (int h = 0; h < NH; h += 4) {
            s0 += qr[h + 0] * ks[(h + 0) * DK + j];
            s1 += qr[h + 1] * ks[(h + 1) * DK + j];
            s2 += qr[h + 2] * ks[(h + 2) * DK + j];
            s3 += qr[h + 3] * ks[(h + 3) * DK + j];
        }
        float s = ((s0 + s1) + (s2 + s3)) * scale;
        float nm = fmaxf(m, s);
        float f = __expf(m - nm);
        float p = __expf(s - nm);
        lsum = lsum * f + p;
        #pragma unroll
        for (int h = 0; h < NH; ++h) acc[h] = acc[h] * f + p * vs[h * DK + j];
        m = nm;
    }

    if (half) {
        m1s[i] = m; l1s[i] = lsum;
        #pragma unroll
        for (int h = 0; h < NH; ++h) acc1s[i][h] = acc[h];
    }
    __syncthreads();
    if (!half) {
        float m1 = m1s[i], l1 = l1s[i];
        float nm = fmaxf(m, m1);               // m is finite (half 0 always has j=0)
        float f0 = __expf(m - nm);
        float f1 = __expf(m1 - nm);            // 0 if half-1 range empty (m1=-inf)
        float rinv = 1.0f / (lsum * f0 + l1 * f1);
        #pragma unroll
        for (int h = 0; h < NH; ++h)
            O[base + h * DK + i] =
                __float2bfloat16((acc[h] * f0 + acc1s[i][h] * f1) * rinv);
    }
}

// ---------------------------------------------------------------------------
// LayerNorm on (sum of nparts fp32 partials + optional bias), bf16 out.
// ---------------------------------------------------------------------------
__global__ __launch_bounds__(256) void layernorm_kernel(
    const float* __restrict__ pa, int nparts,
    const float* __restrict__ addb,
    const float* __restrict__ g, const float* __restrict__ b,
    bf16* __restrict__ Y)
{
    int row = blockIdx.x;
    size_t base = (size_t)row * D_EMB;
    __shared__ float vs[D_EMB];
    __shared__ float buf[256];
    int tid = threadIdx.x;

    float s = 0.0f;
    for (int d = tid; d < D_EMB; d += 256) {
        float v = addb ? addb[d] : 0.0f;
        for (int p = 0; p < nparts; ++p) v += pa[(size_t)p * TOKF + base + d];
        vs[d] = v;
        s += v;
    }
    buf[tid] = s; __syncthreads();
    for (int off = 128; off; off >>= 1) {
        if (tid < off) buf[tid] += buf[tid + off];
        __syncthreads();
    }
    float mean = buf[0] * (1.0f / D_EMB);
    __syncthreads();

    float vsum = 0.0f;
    for (int d = tid; d < D_EMB; d += 256) {
        float t = vs[d] - mean;
        vsum += t * t;
    }
    buf[tid] = vsum; __syncthreads();
    for (int off = 128; off; off >>= 1) {
        if (tid < off) buf[tid] += buf[tid + off];
        __syncthreads();
    }
    float inv = rsqrtf(buf[0] * (1.0f / D_EMB) + 1e-5f);

    for (int d = tid; d < D_EMB; d += 256)
        Y[base + d] = __float2bfloat16(g[d] * (vs[d] - mean) * inv + b[d]);
}

// ---------------------------------------------------------------------------
// Fused logits GEMM + softmax over the sequence axis (axis=1, faithful bug).
// ---------------------------------------------------------------------------
__global__ __launch_bounds__(256) void logits_softmax_kernel(
    const bf16* __restrict__ X, const float* __restrict__ W,
    float* __restrict__ out)
{
    __shared__ __align__(16) bf16 As[128 * 128];   // 32 KB
    __shared__ __align__(16) bf16 Bs[64 * 128];    // 16 KB
    __shared__ float red[4][64];

    int tid = threadIdx.x;
    int w = tid >> 6;
    int lane = tid & 63;
    int fcol = lane & 15;
    int fqu  = lane >> 4;
    int n0 = blockIdx.x * 64;

    float4v acc[2][4];
    #pragma unroll
    for (int fm = 0; fm < 2; ++fm)
        #pragma unroll
        for (int fn = 0; fn < 4; ++fn) acc[fm][fn] = (float4v)0.0f;

    int brow = tid >> 2;          // 0..63
    int q    = tid & 3;
    int gn   = n0 + brow;

    for (int k0 = 0; k0 < D_EMB; k0 += 128) {
        #pragma unroll
        for (int t = 0; t < 8; ++t) {
            int r = t * 16 + (w << 2) + (lane >> 4);
            int s = (lane & 15) ^ (r & 15);
            GLOAD_LDS16(X + (size_t)r * D_EMB + k0 + s * 8,
                        (char*)As + (size_t)(t * 16 + (w << 2)) * 256);
        }
        #pragma unroll
        for (int j = 0; j < 4; ++j) {
            int sL = q * 4 + j;
            union { short8v v; bf16 h[8]; } u;
            if (gn < VOCAB) {
                const float* gp = W + (size_t)gn * D_EMB + k0 + sL * 8;
                float4 f0 = *(const float4*)gp;
                float4 f1 = *(const float4*)(gp + 4);
                u.h[0] = __float2bfloat16(f0.x); u.h[1] = __float2bfloat16(f0.y);
                u.h[2] = __float2bfloat16(f0.z); u.h[3] = __float2bfloat16(f0.w);
                u.h[4] = __float2bfloat16(f1.x); u.h[5] = __float2bfloat16(f1.y);
                u.h[6] = __float2bfloat16(f1.z); u.h[7] = __float2bfloat16(f1.w);
            } else {
                u.v = (short8v)0;
            }
            *(short8v*)((char*)Bs + brow * 256 + ((sL ^ (brow & 15)) << 4)) = u.v;
        }
        __syncthreads();

        #pragma unroll
        for (int kk = 0; kk < 4; ++kk) {
            int slog = kk * 4 + fqu;
            short8v a[2], b[4];
            #pragma unroll
            for (int fm = 0; fm < 2; ++fm) {
                int m = w * 32 + fm * 16 + fcol;
                a[fm] = *(const short8v*)((const char*)As + m * 256 + ((slog ^ (m & 15)) << 4));
            }
            #pragma unroll
            for (int fn = 0; fn < 4; ++fn) {
                int n = fn * 16 + fcol;
                b[fn] = *(const short8v*)((const char*)Bs + n * 256 + ((slog ^ (n & 15)) << 4));
            }
            #pragma unroll
            for (int fm = 0; fm < 2; ++fm)
                #pragma unroll
                for (int fn = 0; fn < 4; ++fn)
                    acc[fm][fn] = __builtin_amdgcn_mfma_f32_16x16x32_bf16(
                        a[fm], b[fn], acc[fm][fn], 0, 0, 0);
        }
        __syncthreads();
    }

    float cmax[4];
    #pragma unroll
    for (int fn = 0; fn < 4; ++fn) {
        float m = -INFINITY;
        #pragma unroll
        for (int fm = 0; fm < 2; ++fm)
            #pragma unroll
            for (int r = 0; r < 4; ++r) m = fmaxf(m, acc[fm][fn][r]);
        m = fmaxf(m, __shfl_xor(m, 16));
        m = fmaxf(m, __shfl_xor(m, 32));
        cmax[fn] = m;
    }
    if (lane < 16) {
        #pragma unroll
        for (int fn = 0; fn < 4; ++fn) red[w][fn * 16 + lane] = cmax[fn];
    }
    __syncthreads();
    #pragma unroll
    for (int fn = 0; fn < 4; ++fn) {
        float m = red[0][fn * 16 + fcol];
        m = fmaxf(m, red[1][fn * 16 + fcol]);
        m = fmaxf(m, red[2][fn * 16 + fcol]);
        m = fmaxf(m, red[3][fn * 16 + fcol]);
        cmax[fn] = m;
    }
    __syncthreads();

    float csum[4];
    #pragma unroll
    for (int fn = 0; fn < 4; ++fn) {
        float s = 0.0f;
        #pragma unroll
        for (int fm = 0; fm < 2; ++fm)
            #pragma unroll
            for (int r = 0; r < 4; ++r) {
                float e = __expf(acc[fm][fn][r] - cmax[fn]);
                acc[fm][fn][r] = e;
                s += e;
            }
        s += __shfl_xor(s, 16);
        s += __shfl_xor(s, 32);
        csum[fn] = s;
    }
    if (lane < 16) {
        #pragma unroll
        for (int fn = 0; fn < 4; ++fn) red[w][fn * 16 + lane] = csum[fn];
    }
    __syncthreads();
    #pragma unroll
    for (int fn = 0; fn < 4; ++fn) {
        float s = red[0][fn * 16 + fcol] + red[1][fn * 16 + fcol]
                + red[2][fn * 16 + fcol] + red[3][fn * 16 + fcol];
        float rinv = 1.0f / s;
        int c = n0 + fn * 16 + fcol;
        if (c < VOCAB) {
            #pragma unroll
            for (int fm = 0; fm < 2; ++fm)
                #pragma unroll
                for (int r = 0; r < 4; ++r) {
                    int rw = w * 32 + fm * 16 + fqu * 4 + r;
                    out[(size_t)rw * VOCAB + c] = acc[fm][fn][r] * rinv;
                }
        }
    }
}

// ---------------------------------------------------------------------------
static inline void launch_gemm(const bf16* A,
                               const bf16* B0, const bf16* B1, const bf16* B2,
                               const float* bias0, const float* bias1, const float* bias2,
                               void* C0, void* C1, void* C2,
                               int M, int N, int K, int relu, int out_bf16,
                               int nout, int ksplit, int kslog, hipStream_t s)
{
    dim3 grid(M / 64, N / 64, nout * ksplit);
    hipLaunchKernelGGL(gemm_mfma_kernel, grid, dim3(256), 0, s,
                       A, B0, B1, B2, bias0, bias1, bias2, C0, C1, C2,
                       M, N, K, relu, out_bf16, ksplit, kslog);
}

extern "C" void kernel_launch(void* const* d_in, const int* in_sizes, int n_in,
                              void* d_out, int out_size, void* d_ws, size_t ws_size,
                              hipStream_t stream)
{
    const float* x_in   = (const float*)d_in[0];
    const float* ctx_in = (const float*)d_in[1];
    const float* Wq1 = (const float*)d_in[2];
    const float* Wk1 = (const float*)d_in[3];
    const float* Wv1 = (const float*)d_in[4];
    const float* Wo1 = (const float*)d_in[5];
    const float* Wq2 = (const float*)d_in[6];
    const float* Wk2 = (const float*)d_in[7];
    const float* Wv2 = (const float*)d_in[8];
    const float* Wo2 = (const float*)d_in[9];
    const float* W_ff1 = (const float*)d_in[10];
    const float* b_ff1 = (const float*)d_in[11];
    const float* W_ff2 = (const float*)d_in[12];
    const float* b_ff2 = (const float*)d_in[13];
    const float* g1  = (const float*)d_in[14];
    const float* be1 = (const float*)d_in[15];
    const float* g2  = (const float*)d_in[16];
    const float* be2 = (const float*)d_in[17];
    const float* g3  = (const float*)d_in[18];
    const float* be3 = (const float*)d_in[19];
    const float* W_lin = (const float*)d_in[20];
    float* out = (float*)d_out;

    const size_t W2 = (size_t)D_EMB * D_EMB;
    const size_t WF = (size_t)DFF * D_EMB;

    char* p = (char*)d_ws;
    bf16* wq1 = (bf16*)p; p += W2 * 2;
    bf16* wk1 = (bf16*)p; p += W2 * 2;
    bf16* wv1 = (bf16*)p; p += W2 * 2;
    bf16* wo1 = (bf16*)p; p += W2 * 2;
    bf16* wq2 = (bf16*)p; p += W2 * 2;
    bf16* wk2 = (bf16*)p; p += W2 * 2;
    bf16* wv2 = (bf16*)p; p += W2 * 2;
    bf16* wo2 = (bf16*)p; p += W2 * 2;
    bf16* wff1 = (bf16*)p; p += WF * 2;
    bf16* wff2 = (bf16*)p; p += WF * 2;
    bf16* wctx = (bf16*)p; p += (size_t)TOKF * 2;
    bf16* X    = (bf16*)p; p += (size_t)TOKF * 2;
    bf16* Att  = (bf16*)p; p += (size_t)TOKF * 2;
    bf16* H    = (bf16*)p; p += (size_t)SEQN * DFF * 2;
    float* Qp  = (float*)p; p += (size_t)4 * TOKF * 4;   // split-K partials (4)
    float* Kp  = (float*)p; p += (size_t)4 * TOKF * 4;
    float* Vp  = (float*)p; p += (size_t)4 * TOKF * 4;
    float* X2p = (float*)p; p += (size_t)8 * TOKF * 4;   // up to 8 (FFN2)
    float* K2p = (float*)p; p += (size_t)2 * TOKF * 4;   // cross K/V partials (2)
    float* V2p = (float*)p; p += (size_t)2 * TOKF * 4;

    const float* ctx7 = ctx_in + (size_t)7 * SEQN * D_EMB;

    // ---- weight conversions (wlin intentionally NOT converted) ----
    {
        CvtArgs a = {};
        a.src[0] = Wq1; a.dst[0] = wq1;  a.src[1] = Wk1; a.dst[1] = wk1;
        a.src[2] = Wv1; a.dst[2] = wv1;  a.src[3] = Wo1; a.dst[3] = wo1;
        a.src[4] = Wq2; a.dst[4] = wq2;  a.src[5] = Wk2; a.dst[5] = wk2;
        a.src[6] = Wv2; a.dst[6] = wv2;  a.src[7] = Wo2; a.dst[7] = wo2;
        int n4 = (int)(W2 / 4);
        hipLaunchKernelGGL(cvt_kernel, dim3((n4 + 255) / 256, 1, 8), dim3(256), 0,
                           stream, a, n4);
    }
    {
        CvtArgs a = {};
        a.src[0] = W_ff1; a.dst[0] = wff1;
        a.src[1] = W_ff2; a.dst[1] = wff2;
        int n4 = (int)(WF / 4);
        hipLaunchKernelGGL(cvt_kernel, dim3((n4 + 255) / 256, 1, 2), dim3(256), 0,
                           stream, a, n4);
    }
    {
        CvtArgs a = {};
        a.src[0] = ctx7; a.dst[0] = wctx;
        int n4 = TOKF / 4;
        hipLaunchKernelGGL(cvt_kernel, dim3((n4 + 255) / 256, 1, 1), dim3(256), 0,
                           stream, a, n4);
    }

    hipLaunchKernelGGL(add_pe_kernel, dim3((SEQN * D_EMB) / 256), dim3(256), 0,
                       stream, x_in, X);

    // cross-attn K2,V2 once: fp32 split-K partials (ksplit=2), consumed
    // directly by the cross-attn kernel (no bf16 materialization pass).
    launch_gemm(wctx, wk2, wv2, wv2, nullptr, nullptr, nullptr,
                K2p, V2p, V2p, SEQN, D_EMB, D_EMB, 0, 0, 2, 2, 1, stream);

    for (int layer = 0; layer < NLAYERS; ++layer) {
        // ---- self attention ----
        launch_gemm(X, wq1, wk1, wv1, nullptr, nullptr, nullptr,
                    Qp, Kp, Vp, SEQN, D_EMB, D_EMB, 0, 0, 3, 4, 2, stream);
        hipLaunchKernelGGL(attn_token_kernel, dim3(SEQN), dim3(256), 0, stream,
                           Qp, Kp, Vp,
                           (const bf16*)nullptr, (const bf16*)nullptr,
                           Att, 1, 4, 4);
        launch_gemm(Att, wo1, wo1, wo1, nullptr, nullptr, nullptr,
                    X2p, X2p, X2p, SEQN, D_EMB, D_EMB, 0, 0, 1, 4, 2, stream);
        hipLaunchKernelGGL(layernorm_kernel, dim3(SEQN), dim3(256), 0, stream,
                           X2p, 4, (const float*)nullptr, g1, be1, X);

        // ---- cross attention ----
        launch_gemm(X, wq2, wq2, wq2, nullptr, nullptr, nullptr,
                    Qp, Qp, Qp, SEQN, D_EMB, D_EMB, 0, 0, 1, 4, 2, stream);
        hipLaunchKernelGGL(attn_token_kernel, dim3(SEQN), dim3(256), 0, stream,
                           Qp, K2p, V2p,
                           (const bf16*)nullptr, (const bf16*)nullptr,
                           Att, 0, 4, 2);
        launch_gemm(Att, wo2, wo2, wo2, nullptr, nullptr, nullptr,
                    X2p, X2p, X2p, SEQN, D_EMB, D_EMB, 0, 0, 1, 4, 2, stream);
        hipLaunchKernelGGL(layernorm_kernel, dim3(SEQN), dim3(256), 0, stream,
                           X2p, 4, (const float*)nullptr, g2, be2, X);

        // ---- FFN ----
        launch_gemm(X, wff1, wff1, wff1, b_ff1, b_ff1, b_ff1,
                    H, H, H, SEQN, DFF, D_EMB, 1, 1, 1, 1, 0, stream);
        launch_gemm(H, wff2, wff2, wff2, nullptr, nullptr, nullptr,
                    X2p, X2p, X2p, SEQN, D_EMB, DFF, 0, 0, 1, 8, 3, stream);
        hipLaunchKernelGGL(layernorm_kernel, dim3(SEQN), dim3(256), 0, stream,
                           X2p, 8, b_ff2, g3, be3, X);
    }

    // fused logits GEMM + sequence-axis softmax (b_lin cancels)
    hipLaunchKernelGGL(logits_softmax_kernel, dim3((VOCAB + 63) / 64), dim3(256),
                       0, stream, X, W_lin, out);
}

// Round 2
// 1437.468 us; speedup vs baseline: 1.2792x; 1.1098x over previous
//
#include <hip/hip_runtime.h>
#include <hip/hip_bf16.h>
#include <math.h>

#define D_EMB 2048
#define NH 16
#define DK 128
#define SEQN 128
#define DFF 8192
#define VOCAB 30000
#define NLAYERS 6
#define TOKF (SEQN * D_EMB)   // 262144 elements

typedef __attribute__((ext_vector_type(8))) short short8v;
typedef __attribute__((ext_vector_type(4))) float float4v;
typedef __hip_bfloat16 bf16;

#define GLOAD_LDS16(g, l)                                                      \
    __builtin_amdgcn_global_load_lds(                                          \
        (const __attribute__((address_space(1))) void*)(g),                    \
        (__attribute__((address_space(3))) void*)(l), 16, 0, 0)

#define WAIT_BAR(n)                                                            \
    do {                                                                       \
        asm volatile("s_waitcnt vmcnt(" #n ")" ::: "memory");                  \
        __builtin_amdgcn_s_barrier();                                          \
        asm volatile("" ::: "memory");                                         \
    } while (0)

// ---------------------------------------------------------------------------
// fp32 -> bf16 conversion, z-batched over up to 8 (src,dst) pairs.
// ---------------------------------------------------------------------------
struct CvtArgs {
    const float* src[8];
    bf16* dst[8];
};

__global__ __launch_bounds__(256) void cvt_kernel(CvtArgs args, int n4) {
    int i = blockIdx.x * 256 + threadIdx.x;
    if (i >= n4) return;
    const float4* s = (const float4*)args.src[blockIdx.z];
    float4 v = s[i];
    union { short4 s4; bf16 h[4]; } u;
    u.h[0] = __float2bfloat16(v.x);
    u.h[1] = __float2bfloat16(v.y);
    u.h[2] = __float2bfloat16(v.z);
    u.h[3] = __float2bfloat16(v.w);
    ((short4*)args.dst[blockIdx.z])[i] = u.s4;
}

// ---------------------------------------------------------------------------
// x[7] + sinusoidal PE -> X [128,2048] bf16
// ---------------------------------------------------------------------------
__global__ __launch_bounds__(256) void add_pe_kernel(const float* __restrict__ x,
                                                     bf16* __restrict__ out) {
    int idx = blockIdx.x * 256 + threadIdx.x;
    int l = idx >> 11;
    int d = idx & 2047;
    float two_i = (float)(d & ~1);
    float div = __expf(-9.210340371976184f * two_i * (1.0f / 2048.0f));
    float ang = (float)l * div;
    float pe = (d & 1) ? cosf(ang) : sinf(ang);
    out[idx] = __float2bfloat16(x[(size_t)7 * SEQN * D_EMB + idx] + pe);
}

// ---------------------------------------------------------------------------
// bf16 MFMA GEMM: C = A[M,K] @ B[N,K]^T, tile 64x64, 4 waves.
// Klocal is ALWAYS 512 (ksplit = K/512): the entire 64x512 A- and B-slices are
// staged into LDS in ONE shot (32 global_load_lds per wave, issued upfront),
// then 4 BK=128 chunks are computed behind counted s_waitcnt vmcnt(24/16/8/0)
// + raw s_barrier. One latency exposure per block, 4 barriers total.
// XCD-chunked bijective blockIdx remap for B-tile L2 locality.
// out_bf16=1: bf16 C with bias/relu. out_bf16=0: fp32 partial at C+kh*M*N.
// ---------------------------------------------------------------------------
__global__ __launch_bounds__(256) void gemm_mfma_kernel(
    const bf16* __restrict__ A,
    const bf16* B0, const bf16* B1, const bf16* B2,
    const float* bias0, const float* bias1, const float* bias2,
    void* C0, void* C1, void* C2,
    int M, int N, int K, int relu, int out_bf16, int ksplit, int kslog)
{
    // bijective XCD-chunked remap (all our grids are multiples of 8)
    int nwg = gridDim.x * gridDim.y * gridDim.z;
    int orig = blockIdx.x + gridDim.x * (blockIdx.y + gridDim.y * blockIdx.z);
    int wg = orig;
    if ((nwg & 7) == 0) wg = (orig & 7) * (nwg >> 3) + (orig >> 3);
    int bx = wg % gridDim.x;
    int t1 = wg / gridDim.x;
    int by = t1 % gridDim.y;
    int bz = t1 / gridDim.y;

    int oi = bz >> kslog;
    int kh = bz & (ksplit - 1);
    int kbase = kh << 9;                       // Klocal = 512

    const bf16* B    = (oi == 0) ? B0    : (oi == 1) ? B1    : B2;
    const float* bias = (oi == 0) ? bias0 : (oi == 1) ? bias1 : bias2;
    void* C          = (oi == 0) ? C0    : (oi == 1) ? C1    : C2;

    __shared__ __align__(16) bf16 As[4][64 * 128];   // 64 KB
    __shared__ __align__(16) bf16 Bs[4][64 * 128];   // 64 KB

    int tid = threadIdx.x;
    int w = tid >> 6;
    int lane = tid & 63;
    int m0 = bx * 64;
    int n0 = by * 64;
    int wm = (w & 1) * 32;
    int wn = (w >> 1) * 32;
    int fcol = lane & 15;
    int fqu  = lane >> 4;
    int rr   = (w << 2) + (lane >> 4);
    int scol = lane & 15;

    float4v acc[2][2];
    acc[0][0] = (float4v)0.0f; acc[0][1] = (float4v)0.0f;
    acc[1][0] = (float4v)0.0f; acc[1][1] = (float4v)0.0f;

    // stage all 4 chunks of both tiles: 8 loads/wave/chunk, 32 total
    #pragma unroll
    for (int c = 0; c < 4; ++c) {
        const bf16* a0 = A + (size_t)m0 * K + kbase + (c << 7);
        const bf16* b0 = B + (size_t)n0 * K + kbase + (c << 7);
        #pragma unroll
        for (int t = 0; t < 4; ++t) {
            int r = t * 16 + rr;
            int s = scol ^ (r & 15);
            GLOAD_LDS16(a0 + (size_t)r * K + s * 8,
                        (char*)As[c] + (size_t)(t * 16 + (w << 2)) * 256);
            GLOAD_LDS16(b0 + (size_t)r * K + s * 8,
                        (char*)Bs[c] + (size_t)(t * 16 + (w << 2)) * 256);
        }
    }

    auto compute_chunk = [&](int c) {
        #pragma unroll
        for (int kk = 0; kk < 4; ++kk) {
            short8v a[2], b[2];
            int slog = kk * 4 + fqu;
            #pragma unroll
            for (int fm = 0; fm < 2; ++fm) {
                int m = wm + fm * 16 + fcol;
                a[fm] = *(const short8v*)((const char*)As[c] + m * 256 + ((slog ^ (m & 15)) << 4));
            }
            #pragma unroll
            for (int fn = 0; fn < 2; ++fn) {
                int n = wn + fn * 16 + fcol;
                b[fn] = *(const short8v*)((const char*)Bs[c] + n * 256 + ((slog ^ (n & 15)) << 4));
            }
            #pragma unroll
            for (int fm = 0; fm < 2; ++fm)
                #pragma unroll
                for (int fn = 0; fn < 2; ++fn)
                    acc[fm][fn] = __builtin_amdgcn_mfma_f32_16x16x32_bf16(
                        a[fm], b[fn], acc[fm][fn], 0, 0, 0);
        }
    };

    WAIT_BAR(24); compute_chunk(0);
    WAIT_BAR(16); compute_chunk(1);
    WAIT_BAR(8);  compute_chunk(2);
    WAIT_BAR(0);  compute_chunk(3);

    int rbase = fqu * 4;
    #pragma unroll
    for (int fm = 0; fm < 2; ++fm) {
        #pragma unroll
        for (int fn = 0; fn < 2; ++fn) {
            int n = n0 + wn + fn * 16 + fcol;
            #pragma unroll
            for (int r = 0; r < 4; ++r) {
                int m = m0 + wm + fm * 16 + rbase + r;
                float v = acc[fm][fn][r];
                if (out_bf16) {
                    v += bias ? bias[n] : 0.0f;
                    if (relu) v = fmaxf(v, 0.0f);
                    ((bf16*)C)[(size_t)m * N + n] = __float2bfloat16(v);
                } else {
                    ((float*)C)[(size_t)kh * M * N + (size_t)m * N + n] = v;
                }
            }
        }
    }
}

// ---------------------------------------------------------------------------
// sum 4 fp32 partials + bias + relu -> bf16 H  (FFN1 epilogue)
// ---------------------------------------------------------------------------
__global__ __launch_bounds__(256) void biasrelu_kernel(
    const float* __restrict__ P, const float* __restrict__ bias,
    bf16* __restrict__ H)
{
    int i4 = blockIdx.x * 256 + threadIdx.x;       // over SEQN*DFF/4 = 262144
    const size_t n4 = (size_t)SEQN * DFF / 4;
    const float4* p = (const float4*)P;
    float4 v0 = p[i4];
    float4 v1 = p[i4 + n4];
    float4 v2 = p[i4 + 2 * n4];
    float4 v3 = p[i4 + 3 * n4];
    float4 b4 = ((const float4*)bias)[i4 & (DFF / 4 - 1)];
    union { short4 s4; bf16 h[4]; } u;
    u.h[0] = __float2bfloat16(fmaxf(v0.x + v1.x + v2.x + v3.x + b4.x, 0.0f));
    u.h[1] = __float2bfloat16(fmaxf(v0.y + v1.y + v2.y + v3.y + b4.y, 0.0f));
    u.h[2] = __float2bfloat16(fmaxf(v0.z + v1.z + v2.z + v3.z + b4.z, 0.0f));
    u.h[3] = __float2bfloat16(fmaxf(v0.w + v1.w + v2.w + v3.w + b4.w, 0.0f));
    ((short4*)H)[i4] = u.s4;
}

// ---------------------------------------------------------------------------
// Per-token "attention" (faithful bug). One-pass online softmax, j-loop split
// across two thread-halves, float4-vectorized over j (uniform-address LDS
// b128 broadcasts). Q/K/V arrive as fp32 split-K partial stacks.
// ---------------------------------------------------------------------------
__global__ __launch_bounds__(256) void attn_token_kernel(
    const float* __restrict__ qp,
    const float* __restrict__ kp, const float* __restrict__ vp,
    bf16* __restrict__ O, int causal, int qparts, int kvparts)
{
    int l = blockIdx.x;
    int tid = threadIdx.x;
    int i = tid & 127;
    int half = tid >> 7;
    __shared__ __align__(16) float qs[D_EMB];
    __shared__ __align__(16) float ks[D_EMB];
    __shared__ __align__(16) float vs[D_EMB];
    __shared__ float m1s[128], l1s[128];
    __shared__ float acc1s[128][NH + 1];
    size_t base = (size_t)l * D_EMB;

    for (int d4 = tid; d4 < D_EMB / 4; d4 += 256) {
        float4 q = {0.0f, 0.0f, 0.0f, 0.0f};
        for (int p = 0; p < qparts; ++p) {
            float4 t = ((const float4*)(qp + (size_t)p * TOKF + base))[d4];
            q.x += t.x; q.y += t.y; q.z += t.z; q.w += t.w;
        }
        ((float4*)qs)[d4] = q;
        float4 kv = {0.0f, 0.0f, 0.0f, 0.0f}, vv = {0.0f, 0.0f, 0.0f, 0.0f};
        for (int p = 0; p < kvparts; ++p) {
            float4 t = ((const float4*)(kp + (size_t)p * TOKF + base))[d4];
            kv.x += t.x; kv.y += t.y; kv.z += t.z; kv.w += t.w;
            float4 s = ((const float4*)(vp + (size_t)p * TOKF + base))[d4];
            vv.x += s.x; vv.y += s.y; vv.z += s.z; vv.w += s.w;
        }
        ((float4*)ks)[d4] = kv;
        ((float4*)vs)[d4] = vv;
    }
    __syncthreads();

    const float scale = 0.088388347648318447f;  // 1/sqrt(128)
    float qr[NH];
    #pragma unroll
    for (int h = 0; h < NH; ++h) qr[h] = qs[h * DK + i];

    int jmax = causal ? (i + 1) : DK;
    int j0 = half * 64;
    int j1 = (jmax < j0 + 64) ? jmax : (j0 + 64);

    float m = -INFINITY, lsum = 0.0f;
    float acc[NH];
    #pragma unroll
    for (int h = 0; h < NH; ++h) acc[h] = 0.0f;

    for (int j = j0; j < j1; j += 4) {
        float4 s4 = {0.0f, 0.0f, 0.0f, 0.0f};
        #pragma unroll
        for (int h = 0; h < NH; ++h) {
            float4 kv = *(const float4*)&ks[h * DK + j];
            s4.x += qr[h] * kv.x; s4.y += qr[h] * kv.y;
            s4.z += qr[h] * kv.z; s4.w += qr[h] * kv.w;
        }
        float sv0 = s4.x * scale;
        float sv1 = (j + 1 < j1) ? s4.y * scale : -INFINITY;
        float sv2 = (j + 2 < j1) ? s4.z * scale : -INFINITY;
        float sv3 = (j + 3 < j1) ? s4.w * scale : -INFINITY;
        float mx = fmaxf(fmaxf(sv0, sv1), fmaxf(sv2, sv3));
        float nm = fmaxf(m, mx);
        float f  = __expf(m - nm);
        float p0 = __expf(sv0 - nm);
        float p1 = __expf(sv1 - nm);
        float p2 = __expf(sv2 - nm);
        float p3 = __expf(sv3 - nm);
        lsum = lsum * f + ((p0 + p1) + (p2 + p3));
        #pragma unroll
        for (int h = 0; h < NH; ++h) {
            float4 vv = *(const float4*)&vs[h * DK + j];
            acc[h] = acc[h] * f + ((p0 * vv.x + p1 * vv.y) + (p2 * vv.z + p3 * vv.w));
        }
        m = nm;
    }

    if (half) {
        m1s[i] = m; l1s[i] = lsum;
        #pragma unroll
        for (int h = 0; h < NH; ++h) acc1s[i][h] = acc[h];
    }
    __syncthreads();
    if (!half) {
        float m1 = m1s[i], l1 = l1s[i];
        float nm = fmaxf(m, m1);               // m finite (half 0 has j=0)
        float f0 = __expf(m - nm);
        float f1 = __expf(m1 - nm);            // 0 if half-1 range empty
        float rinv = 1.0f / (lsum * f0 + l1 * f1);
        #pragma unroll
        for (int h = 0; h < NH; ++h)
            O[base + h * DK + i] =
                __float2bfloat16((acc[h] * f0 + acc1s[i][h] * f1) * rinv);
    }
}

// ---------------------------------------------------------------------------
// LayerNorm on (sum of nparts fp32 partials + optional bias), bf16 out.
// float4-vectorized loads/stores.
// ---------------------------------------------------------------------------
__global__ __launch_bounds__(256) void layernorm_kernel(
    const float* __restrict__ pa, int nparts,
    const float* __restrict__ addb,
    const float* __restrict__ g, const float* __restrict__ b,
    bf16* __restrict__ Y)
{
    int row = blockIdx.x;
    size_t base = (size_t)row * D_EMB;
    __shared__ __align__(16) float4 vs4[D_EMB / 4];
    __shared__ float buf[256];
    int tid = threadIdx.x;

    float s = 0.0f;
    for (int d4 = tid; d4 < D_EMB / 4; d4 += 256) {
        float4 v = {0.0f, 0.0f, 0.0f, 0.0f};
        if (addb) v = ((const float4*)addb)[d4];
        for (int p = 0; p < nparts; ++p) {
            float4 t = ((const float4*)(pa + (size_t)p * TOKF + base))[d4];
            v.x += t.x; v.y += t.y; v.z += t.z; v.w += t.w;
        }
        vs4[d4] = v;
        s += (v.x + v.y) + (v.z + v.w);
    }
    buf[tid] = s; __syncthreads();
    for (int off = 128; off; off >>= 1) {
        if (tid < off) buf[tid] += buf[tid + off];
        __syncthreads();
    }
    float mean = buf[0] * (1.0f / D_EMB);
    __syncthreads();

    float vsum = 0.0f;
    for (int d4 = tid; d4 < D_EMB / 4; d4 += 256) {
        float4 v = vs4[d4];
        float t0 = v.x - mean, t1 = v.y - mean, t2 = v.z - mean, t3 = v.w - mean;
        vsum += (t0 * t0 + t1 * t1) + (t2 * t2 + t3 * t3);
    }
    buf[tid] = vsum; __syncthreads();
    for (int off = 128; off; off >>= 1) {
        if (tid < off) buf[tid] += buf[tid + off];
        __syncthreads();
    }
    float inv = rsqrtf(buf[0] * (1.0f / D_EMB) + 1e-5f);

    for (int d4 = tid; d4 < D_EMB / 4; d4 += 256) {
        float4 v = vs4[d4];
        float4 g4 = ((const float4*)g)[d4];
        float4 b4 = ((const float4*)b)[d4];
        union { short4 s4; bf16 h[4]; } u;
        u.h[0] = __float2bfloat16(g4.x * (v.x - mean) * inv + b4.x);
        u.h[1] = __float2bfloat16(g4.y * (v.y - mean) * inv + b4.y);
        u.h[2] = __float2bfloat16(g4.z * (v.z - mean) * inv + b4.z);
        u.h[3] = __float2bfloat16(g4.w * (v.w - mean) * inv + b4.w);
        ((short4*)(Y + base))[d4] = u.s4;
    }
}

// ---------------------------------------------------------------------------
// Fused logits GEMM + softmax over the sequence axis (axis=1, faithful bug).
// ---------------------------------------------------------------------------
__global__ __launch_bounds__(256) void logits_softmax_kernel(
    const bf16* __restrict__ X, const float* __restrict__ W,
    float* __restrict__ out)
{
    __shared__ __align__(16) bf16 As[128 * 128];   // 32 KB
    __shared__ __align__(16) bf16 Bs[64 * 128];    // 16 KB
    __shared__ float red[4][64];

    int tid = threadIdx.x;
    int w = tid >> 6;
    int lane = tid & 63;
    int fcol = lane & 15;
    int fqu  = lane >> 4;
    int n0 = blockIdx.x * 64;

    float4v acc[2][4];
    #pragma unroll
    for (int fm = 0; fm < 2; ++fm)
        #pragma unroll
        for (int fn = 0; fn < 4; ++fn) acc[fm][fn] = (float4v)0.0f;

    int brow = tid >> 2;          // 0..63
    int q    = tid & 3;
    int gn   = n0 + brow;

    for (int k0 = 0; k0 < D_EMB; k0 += 128) {
        #pragma unroll
        for (int t = 0; t < 8; ++t) {
            int r = t * 16 + (w << 2) + (lane >> 4);
            int s = (lane & 15) ^ (r & 15);
            GLOAD_LDS16(X + (size_t)r * D_EMB + k0 + s * 8,
                        (char*)As + (size_t)(t * 16 + (w << 2)) * 256);
        }
        #pragma unroll
        for (int j = 0; j < 4; ++j) {
            int sL = q * 4 + j;
            union { short8v v; bf16 h[8]; } u;
            if (gn < VOCAB) {
                const float* gp = W + (size_t)gn * D_EMB + k0 + sL * 8;
                float4 f0 = *(const float4*)gp;
                float4 f1 = *(const float4*)(gp + 4);
                u.h[0] = __float2bfloat16(f0.x); u.h[1] = __float2bfloat16(f0.y);
                u.h[2] = __float2bfloat16(f0.z); u.h[3] = __float2bfloat16(f0.w);
                u.h[4] = __float2bfloat16(f1.x); u.h[5] = __float2bfloat16(f1.y);
                u.h[6] = __float2bfloat16(f1.z); u.h[7] = __float2bfloat16(f1.w);
            } else {
                u.v = (short8v)0;
            }
            *(short8v*)((char*)Bs + brow * 256 + ((sL ^ (brow & 15)) << 4)) = u.v;
        }
        __syncthreads();

        #pragma unroll
        for (int kk = 0; kk < 4; ++kk) {
            int slog = kk * 4 + fqu;
            short8v a[2], b[4];
            #pragma unroll
            for (int fm = 0; fm < 2; ++fm) {
                int m = w * 32 + fm * 16 + fcol;
                a[fm] = *(const short8v*)((const char*)As + m * 256 + ((slog ^ (m & 15)) << 4));
            }
            #pragma unroll
            for (int fn = 0; fn < 4; ++fn) {
                int n = fn * 16 + fcol;
                b[fn] = *(const short8v*)((const char*)Bs + n * 256 + ((slog ^ (n & 15)) << 4));
            }
            #pragma unroll
            for (int fm = 0; fm < 2; ++fm)
                #pragma unroll
                for (int fn = 0; fn < 4; ++fn)
                    acc[fm][fn] = __builtin_amdgcn_mfma_f32_16x16x32_bf16(
                        a[fm], b[fn], acc[fm][fn], 0, 0, 0);
        }
        __syncthreads();
    }

    float cmax[4];
    #pragma unroll
    for (int fn = 0; fn < 4; ++fn) {
        float m = -INFINITY;
        #pragma unroll
        for (int fm = 0; fm < 2; ++fm)
            #pragma unroll
            for (int r = 0; r < 4; ++r) m = fmaxf(m, acc[fm][fn][r]);
        m = fmaxf(m, __shfl_xor(m, 16));
        m = fmaxf(m, __shfl_xor(m, 32));
        cmax[fn] = m;
    }
    if (lane < 16) {
        #pragma unroll
        for (int fn = 0; fn < 4; ++fn) red[w][fn * 16 + lane] = cmax[fn];
    }
    __syncthreads();
    #pragma unroll
    for (int fn = 0; fn < 4; ++fn) {
        float m = red[0][fn * 16 + fcol];
        m = fmaxf(m, red[1][fn * 16 + fcol]);
        m = fmaxf(m, red[2][fn * 16 + fcol]);
        m = fmaxf(m, red[3][fn * 16 + fcol]);
        cmax[fn] = m;
    }
    __syncthreads();

    float csum[4];
    #pragma unroll
    for (int fn = 0; fn < 4; ++fn) {
        float s = 0.0f;
        #pragma unroll
        for (int fm = 0; fm < 2; ++fm)
            #pragma unroll
            for (int r = 0; r < 4; ++r) {
                float e = __expf(acc[fm][fn][r] - cmax[fn]);
                acc[fm][fn][r] = e;
                s += e;
            }
        s += __shfl_xor(s, 16);
        s += __shfl_xor(s, 32);
        csum[fn] = s;
    }
    if (lane < 16) {
        #pragma unroll
        for (int fn = 0; fn < 4; ++fn) red[w][fn * 16 + lane] = csum[fn];
    }
    __syncthreads();
    #pragma unroll
    for (int fn = 0; fn < 4; ++fn) {
        float s = red[0][fn * 16 + fcol] + red[1][fn * 16 + fcol]
                + red[2][fn * 16 + fcol] + red[3][fn * 16 + fcol];
        float rinv = 1.0f / s;
        int c = n0 + fn * 16 + fcol;
        if (c < VOCAB) {
            #pragma unroll
            for (int fm = 0; fm < 2; ++fm)
                #pragma unroll
                for (int r = 0; r < 4; ++r) {
                    int rw = w * 32 + fm * 16 + fqu * 4 + r;
                    out[(size_t)rw * VOCAB + c] = acc[fm][fn][r] * rinv;
                }
        }
    }
}

// ---------------------------------------------------------------------------
static inline void launch_gemm(const bf16* A,
                               const bf16* B0, const bf16* B1, const bf16* B2,
                               const float* bias0, const float* bias1, const float* bias2,
                               void* C0, void* C1, void* C2,
                               int M, int N, int K, int relu, int out_bf16,
                               int nout, hipStream_t s)
{
    int ksplit = K >> 9;                       // Klocal = 512 always
    int kslog = (ksplit == 4) ? 2 : (ksplit == 16) ? 4 : (ksplit == 8) ? 3 : 0;
    dim3 grid(M / 64, N / 64, nout * ksplit);
    hipLaunchKernelGGL(gemm_mfma_kernel, grid, dim3(256), 0, s,
                       A, B0, B1, B2, bias0, bias1, bias2, C0, C1, C2,
                       M, N, K, relu, out_bf16, ksplit, kslog);
}

extern "C" void kernel_launch(void* const* d_in, const int* in_sizes, int n_in,
                              void* d_out, int out_size, void* d_ws, size_t ws_size,
                              hipStream_t stream)
{
    const float* x_in   = (const float*)d_in[0];
    const float* ctx_in = (const float*)d_in[1];
    const float* Wq1 = (const float*)d_in[2];
    const float* Wk1 = (const float*)d_in[3];
    const float* Wv1 = (const float*)d_in[4];
    const float* Wo1 = (const float*)d_in[5];
    const float* Wq2 = (const float*)d_in[6];
    const float* Wk2 = (const float*)d_in[7];
    const float* Wv2 = (const float*)d_in[8];
    const float* Wo2 = (const float*)d_in[9];
    const float* W_ff1 = (const float*)d_in[10];
    const float* b_ff1 = (const float*)d_in[11];
    const float* W_ff2 = (const float*)d_in[12];
    const float* b_ff2 = (const float*)d_in[13];
    const float* g1  = (const float*)d_in[14];
    const float* be1 = (const float*)d_in[15];
    const float* g2  = (const float*)d_in[16];
    const float* be2 = (const float*)d_in[17];
    const float* g3  = (const float*)d_in[18];
    const float* be3 = (const float*)d_in[19];
    const float* W_lin = (const float*)d_in[20];
    float* out = (float*)d_out;

    const size_t W2 = (size_t)D_EMB * D_EMB;
    const size_t WF = (size_t)DFF * D_EMB;

    char* p = (char*)d_ws;
    bf16* wq1 = (bf16*)p; p += W2 * 2;
    bf16* wk1 = (bf16*)p; p += W2 * 2;
    bf16* wv1 = (bf16*)p; p += W2 * 2;
    bf16* wo1 = (bf16*)p; p += W2 * 2;
    bf16* wq2 = (bf16*)p; p += W2 * 2;
    bf16* wk2 = (bf16*)p; p += W2 * 2;
    bf16* wv2 = (bf16*)p; p += W2 * 2;
    bf16* wo2 = (bf16*)p; p += W2 * 2;
    bf16* wff1 = (bf16*)p; p += WF * 2;
    bf16* wff2 = (bf16*)p; p += WF * 2;
    bf16* wctx = (bf16*)p; p += (size_t)TOKF * 2;
    bf16* X    = (bf16*)p; p += (size_t)TOKF * 2;
    bf16* Att  = (bf16*)p; p += (size_t)TOKF * 2;
    bf16* H    = (bf16*)p; p += (size_t)SEQN * DFF * 2;
    float* Qp  = (float*)p; p += (size_t)4 * TOKF * 4;    // split-K partials
    float* Kp  = (float*)p; p += (size_t)4 * TOKF * 4;
    float* Vp  = (float*)p; p += (size_t)4 * TOKF * 4;
    float* X2p = (float*)p; p += (size_t)16 * TOKF * 4;   // up to 16 (FFN2)
    float* K2p = (float*)p; p += (size_t)4 * TOKF * 4;    // cross K/V partials
    float* V2p = (float*)p; p += (size_t)4 * TOKF * 4;
    float* FFp = (float*)p; p += (size_t)4 * SEQN * DFF * 4;  // FFN1 partials

    const float* ctx7 = ctx_in + (size_t)7 * SEQN * D_EMB;

    // ---- weight conversions (wlin intentionally NOT converted) ----
    {
        CvtArgs a = {};
        a.src[0] = Wq1; a.dst[0] = wq1;  a.src[1] = Wk1; a.dst[1] = wk1;
        a.src[2] = Wv1; a.dst[2] = wv1;  a.src[3] = Wo1; a.dst[3] = wo1;
        a.src[4] = Wq2; a.dst[4] = wq2;  a.src[5] = Wk2; a.dst[5] = wk2;
        a.src[6] = Wv2; a.dst[6] = wv2;  a.src[7] = Wo2; a.dst[7] = wo2;
        int n4 = (int)(W2 / 4);
        hipLaunchKernelGGL(cvt_kernel, dim3((n4 + 255) / 256, 1, 8), dim3(256), 0,
                           stream, a, n4);
    }
    {
        CvtArgs a = {};
        a.src[0] = W_ff1; a.dst[0] = wff1;
        a.src[1] = W_ff2; a.dst[1] = wff2;
        int n4 = (int)(WF / 4);
        hipLaunchKernelGGL(cvt_kernel, dim3((n4 + 255) / 256, 1, 2), dim3(256), 0,
                           stream, a, n4);
    }
    {
        CvtArgs a = {};
        a.src[0] = ctx7; a.dst[0] = wctx;
        int n4 = TOKF / 4;
        hipLaunchKernelGGL(cvt_kernel, dim3((n4 + 255) / 256, 1, 1), dim3(256), 0,
                           stream, a, n4);
    }

    hipLaunchKernelGGL(add_pe_kernel, dim3((SEQN * D_EMB) / 256), dim3(256), 0,
                       stream, x_in, X);

    // cross-attn K2,V2 once: fp32 split-K partials (ks=4)
    launch_gemm(wctx, wk2, wv2, wv2, nullptr, nullptr, nullptr,
                K2p, V2p, V2p, SEQN, D_EMB, D_EMB, 0, 0, 2, stream);

    for (int layer = 0; layer < NLAYERS; ++layer) {
        // ---- self attention ----
        launch_gemm(X, wq1, wk1, wv1, nullptr, nullptr, nullptr,
                    Qp, Kp, Vp, SEQN, D_EMB, D_EMB, 0, 0, 3, stream);
        hipLaunchKernelGGL(attn_token_kernel, dim3(SEQN), dim3(256), 0, stream,
                           Qp, Kp, Vp, Att, 1, 4, 4);
        launch_gemm(Att, wo1, wo1, wo1, nullptr, nullptr, nullptr,
                    X2p, X2p, X2p, SEQN, D_EMB, D_EMB, 0, 0, 1, stream);
        hipLaunchKernelGGL(layernorm_kernel, dim3(SEQN), dim3(256), 0, stream,
                           X2p, 4, (const float*)nullptr, g1, be1, X);

        // ---- cross attention ----
        launch_gemm(X, wq2, wq2, wq2, nullptr, nullptr, nullptr,
                    Qp, Qp, Qp, SEQN, D_EMB, D_EMB, 0, 0, 1, stream);
        hipLaunchKernelGGL(attn_token_kernel, dim3(SEQN), dim3(256), 0, stream,
                           Qp, K2p, V2p, Att, 0, 4, 4);
        launch_gemm(Att, wo2, wo2, wo2, nullptr, nullptr, nullptr,
                    X2p, X2p, X2p, SEQN, D_EMB, D_EMB, 0, 0, 1, stream);
        hipLaunchKernelGGL(layernorm_kernel, dim3(SEQN), dim3(256), 0, stream,
                           X2p, 4, (const float*)nullptr, g2, be2, X);

        // ---- FFN ----
        launch_gemm(X, wff1, wff1, wff1, nullptr, nullptr, nullptr,
                    FFp, FFp, FFp, SEQN, DFF, D_EMB, 0, 0, 1, stream);
        hipLaunchKernelGGL(biasrelu_kernel, dim3((SEQN * DFF / 4) / 256), dim3(256),
                           0, stream, FFp, b_ff1, H);
        launch_gemm(H, wff2, wff2, wff2, nullptr, nullptr, nullptr,
                    X2p, X2p, X2p, SEQN, D_EMB, DFF, 0, 0, 1, stream);
        hipLaunchKernelGGL(layernorm_kernel, dim3(SEQN), dim3(256), 0, stream,
                           X2p, 16, b_ff2, g3, be3, X);
    }

    // fused logits GEMM + sequence-axis softmax (b_lin cancels)
    hipLaunchKernelGGL(logits_softmax_kernel, dim3((VOCAB + 63) / 64), dim3(256),
                       0, stream, X, W_lin, out);
}